// Round 10
// baseline (458.205 us; speedup 1.0000x reference)
//
#include <hip/hip_runtime.h>
#include <stdint.h>

// Sizes (fixed by the problem)
#define N_PATCH 8192
#define DIM     1024
#define HID     512
#define NHEAD   16

using short8 = __attribute__((ext_vector_type(8))) short;
using f32x4  = __attribute__((ext_vector_type(4))) float;

__device__ __forceinline__ unsigned short f2bf(float f) {
  unsigned u = __float_as_uint(f);
  u = u + 0x7fffu + ((u >> 16) & 1u);   // round-to-nearest-even
  return (unsigned short)(u >> 16);
}

// global -> LDS direct copy, 16B per lane (CK addrspace-cast pattern)
__device__ __forceinline__ void gload_lds16(const void* g, void* l) {
  __builtin_amdgcn_global_load_lds(
      reinterpret_cast<const __attribute__((address_space(1))) void*>(
          reinterpret_cast<uintptr_t>(g)),
      reinterpret_cast<__attribute__((address_space(3))) void*>(
          reinterpret_cast<uintptr_t>(l)),
      16, 0, 0);
}

// ---------------- fused prep: x fp32->bf16 (blocks 0..2047) + weight pack (2048..4095) ----
// pack: Wpt[k][c][d] bf16, c = (h>>4)*32 + u*16 + (h&15), u=0:V 1:U
__global__ void prep_kernel(const float* __restrict__ x,
                            unsigned short* __restrict__ xb,
                            const float* __restrict__ Vw,
                            const float* __restrict__ Uw,
                            unsigned short* __restrict__ Wpt) {
  __shared__ unsigned short T[128][68];
  const int bid = blockIdx.x;
  const int t = threadIdx.x;
  if (bid < 2048) {
    const int total4 = (N_PATCH * DIM) / 4;
    for (int i = bid * 256 + t; i < total4; i += 2048 * 256) {
      float4 v = ((const float4*)x)[i];
      ushort4 o;
      o.x = f2bf(v.x); o.y = f2bf(v.y); o.z = f2bf(v.z); o.w = f2bf(v.w);
      ((ushort4*)xb)[i] = o;
    }
    return;
  }
  const int idx = bid - 2048;
  const int hc = idx & 7;          // h chunk of 64
  const int dc = (idx >> 3) & 15;  // d chunk of 64
  const int k  = idx >> 7;         // head
  const int d0 = dc * 64, h0 = hc * 64;
  const size_t base = (size_t)k * DIM * HID;
  for (int u = 0; u < 2; ++u) {
    const float* W = u ? Uw : Vw;
    #pragma unroll
    for (int i = 0; i < 16; ++i) {
      int ii = i * 256 + t;
      int dd = ii >> 6, hh = ii & 63;
      float v = W[base + (size_t)(d0 + dd) * HID + h0 + hh];
      int cl = ((hh >> 4) << 5) + (u << 4) + (hh & 15);
      T[cl][dd] = f2bf(v);
    }
  }
  __syncthreads();
  const size_t obase = ((size_t)k * 1024 + hc * 128) * DIM + d0;
  #pragma unroll
  for (int i = 0; i < 8; ++i) {
    int ii = i * 1024 + t * 4;
    int cl = ii >> 6, dd = ii & 63;
    ushort4 o;
    o.x = T[cl][dd]; o.y = T[cl][dd + 1]; o.z = T[cl][dd + 2]; o.w = T[cl][dd + 3];
    *(ushort4*)&Wpt[obase + (size_t)cl * DIM + dd] = o;
  }
}

// ---------------- main GEMM + gated epilogue -> score partials ----------------
// 256x256 tile, BK=64, 16 waves (4M x 4N, 64x64 out/wave -> 64 AGPR acc),
// 1024 threads, 4 waves/SIMD target, 3-bit XOR swizzle, one barrier/K-tile,
// L2-aware 2D block map (16mt x 16ct rectangle per XCD).
__global__ __launch_bounds__(1024, 4) void gemm_scores_kernel(
    const unsigned short* __restrict__ xb,
    const unsigned short* __restrict__ Wpt,
    const float* __restrict__ Vb, const float* __restrict__ Ub,
    const float* __restrict__ ww, float* __restrict__ part) {
  __shared__ unsigned short As[2][16384];   // 64 KB (256 rows x 64k)
  __shared__ unsigned short Bs[2][16384];   // 64 KB
  const int bid = blockIdx.x;
  const int x8 = bid & 7;           // XCD (round-robin dispatch assumption)
  const int s  = (bid >> 3) & 31;   // concurrent window slot within XCD
  const int w  = bid >> 8;          // epoch 0..7
  const int mt = (x8 & 1) * 16 + (w & 1) * 8 + (s >> 2);   // 0..31
  const int ct = (x8 >> 1) * 16 + (w >> 1) * 4 + (s & 3);  // 0..63
  const int kh = ct >> 2, cb = ct & 3;
  const int tid = threadIdx.x;
  const int wv = tid >> 6, lane = tid & 63;
  const int wr = wv >> 2, wc = wv & 3;         // 4 x 4 wave grid
  const int l15 = lane & 15, l4 = lane >> 4;

  const unsigned short* Ab = xb + (size_t)mt * 256 * DIM;
  const unsigned short* Bb = Wpt + (size_t)ct * 256 * DIM;

  const f32x4 vzero = {0.f, 0.f, 0.f, 0.f};
  f32x4 acc[4][4];   // 64 regs (AGPR): rows f*16, cols nf*16
  #pragma unroll
  for (int i = 0; i < 4; ++i)
    #pragma unroll
    for (int j = 0; j < 4; ++j) acc[i][j] = vzero;

  // ---- staging: chunk = 16KB (128 rows x 64k), 1 gload_lds16/thread/chunk,
  //      linear LDS dest, inverse-swizzled global source (elem k ^= ((r>>1)&7)<<3)
  auto stageA = [&](int t, int mh) {
    const int buf = t & 1, db = t << 6;
    const int r = mh * 128 + (tid >> 3);
    const int ksrc = ((tid & 7) * 8) ^ (((r >> 1) & 7) << 3);
    char* lds = (char*)&As[buf][0] + mh * 16384 + wv * 1024;
    gload_lds16(Ab + (size_t)r * DIM + db + ksrc, lds);
  };
  auto stageB = [&](int t, int nh) {
    const int buf = t & 1, db = t << 6;
    const int r = nh * 128 + (tid >> 3);
    const int ksrc = ((tid & 7) * 8) ^ (((r >> 1) & 7) << 3);
    char* lds = (char*)&Bs[buf][0] + nh * 16384 + wv * 1024;
    gload_lds16(Bb + (size_t)r * DIM + db + ksrc, lds);
  };

  // ---- hoisted swizzled read addresses (per-lane constants) ----
  const int swz = ((l15 >> 1) & 7) << 4;       // byte bits 4-6
  const int kb0 = (l4 * 16) ^ swz;
  const int aB0 = wr * 8192 + l15 * 128 + kb0;   // rows wr*64.., frag f -> +f*2048, ks -> ^64
  const int bB0 = wc * 8192 + l15 * 128 + kb0;

  short8 a[8], b[4];
  auto LDA = [&](int buf) {                    // all 8 A reads: a[f*2+ks]
    const char* base = (const char*)&As[buf][0];
    #pragma unroll
    for (int f = 0; f < 4; ++f) {
      a[f * 2 + 0] = *(const short8*)(base + (aB0 + f * 2048));
      a[f * 2 + 1] = *(const short8*)(base + ((aB0 + f * 2048) ^ 64));
    }
  };
  auto LDB = [&](int buf, int half) {          // 4 B reads: b[g*2+ks], nf = half*2+g
    const char* base = (const char*)&Bs[buf][0] + half * 4096;
    #pragma unroll
    for (int g = 0; g < 2; ++g) {
      b[g * 2 + 0] = *(const short8*)(base + (bB0 + g * 2048));
      b[g * 2 + 1] = *(const short8*)(base + ((bB0 + g * 2048) ^ 64));
    }
  };

  // ---- prologue: stage tiles 0 and 1 (4 chunks each); one conservative drain ----
  stageA(0, 0); stageA(0, 1); stageB(0, 0); stageB(0, 1);
  stageA(1, 0); stageA(1, 1); stageB(1, 0); stageB(1, 1);
  __syncthreads();   // vmcnt(0) + barrier: both tiles resident

  // ---- main loop: one barrier per K-tile; compiler schedules the region ----
  for (int u = 0; u < 16; ++u) {
    const int buf = u & 1;
    // stage-first: tile u+1 into buf^1, HBM latency hides under whole body
    if (u < 15) { stageA(u + 1, 0); stageA(u + 1, 1); stageB(u + 1, 0); stageB(u + 1, 1); }
    LDA(buf);
    #pragma unroll
    for (int half = 0; half < 2; ++half) {
      LDB(buf, half);
      __builtin_amdgcn_s_setprio(1);
      #pragma unroll
      for (int f = 0; f < 4; ++f)
        #pragma unroll
        for (int g = 0; g < 2; ++g)
          #pragma unroll
          for (int ks = 0; ks < 2; ++ks)
            acc[f][half * 2 + g] = __builtin_amdgcn_mfma_f32_16x16x32_bf16(
                a[f * 2 + ks], b[g * 2 + ks], acc[f][half * 2 + g], 0, 0, 0);
      __builtin_amdgcn_s_setprio(0);
    }
    __syncthreads();   // vmcnt(0) (stage u+1 resident) + read-retire fence
  }

  // ---- gated epilogue: tanh(AV+Vb)*sigmoid(AU+Ub)*ww, reduce 16 lanes ----
  float partial[4][4];
  #pragma unroll
  for (int f = 0; f < 4; ++f)
    #pragma unroll
    for (int r = 0; r < 4; ++r) partial[f][r] = 0.f;

  #pragma unroll
  for (int p = 0; p < 2; ++p) {
    const int hl = (cb * 8 + wc * 2 + p) * 16 + l15;   // head-local h
    const float vb  = Vb[kh * HID + hl];
    const float ub  = Ub[kh * HID + hl];
    const float wwv = ww[kh * HID + hl];
    #pragma unroll
    for (int f = 0; f < 4; ++f)
      #pragma unroll
      for (int r = 0; r < 4; ++r) {
        const float xv = acc[f][2 * p][r] + vb;
        const float e2 = __expf(2.f * xv);
        const float av = 1.f - 2.f / (e2 + 1.f);       // tanh
        const float xu = acc[f][2 * p + 1][r] + ub;
        const float au = 1.f / (1.f + __expf(-xu));    // sigmoid
        partial[f][r] += av * au * wwv;
      }
  }
  #pragma unroll
  for (int s2 = 1; s2 < 16; s2 <<= 1)
    #pragma unroll
    for (int f = 0; f < 4; ++f)
      #pragma unroll
      for (int r = 0; r < 4; ++r)
        partial[f][r] += __shfl_xor(partial[f][r], s2, 64);

  if (l15 == 0) {
    const int j = cb * 4 + wc;   // 0..15 partial slot
    float* dst = part + ((size_t)j * NHEAD + kh) * N_PATCH;
    const int rbase = mt * 256 + wr * 64 + l4 * 4;
    #pragma unroll
    for (int f = 0; f < 4; ++f)
      #pragma unroll
      for (int r = 0; r < 4; ++r)
        dst[rbase + f * 16 + r] = partial[f][r];
  }
}

// ---------------- scores + per-chunk softmax partials (128 blocks) ----------------
__global__ void scores_part_kernel(const float* __restrict__ part,
                                   float* __restrict__ scores,
                                   float* __restrict__ spart) {
  const int k = blockIdx.x >> 3, c = blockIdx.x & 7;
  const int t = threadIdx.x;   // 256
  __shared__ float shm[4], shs[4];
  float v[4];
  float mx = -1e30f;
  #pragma unroll
  for (int i = 0; i < 4; ++i) {
    const int n = c * 1024 + i * 256 + t;
    float s = 0.f;
    #pragma unroll
    for (int j = 0; j < 16; ++j) s += part[((size_t)j * NHEAD + k) * N_PATCH + n];
    v[i] = s;
    scores[(size_t)k * N_PATCH + n] = s;
    mx = fmaxf(mx, s);
  }
  #pragma unroll
  for (int sft = 32; sft; sft >>= 1) mx = fmaxf(mx, __shfl_xor(mx, sft, 64));
  const int wv = t >> 6;
  if ((t & 63) == 0) shm[wv] = mx;
  __syncthreads();
  mx = fmaxf(fmaxf(shm[0], shm[1]), fmaxf(shm[2], shm[3]));
  float sum = 0.f;
  #pragma unroll
  for (int i = 0; i < 4; ++i) sum += __expf(v[i] - mx);
  #pragma unroll
  for (int sft = 32; sft; sft >>= 1) sum += __shfl_xor(sum, sft, 64);
  if ((t & 63) == 0) shs[wv] = sum;
  __syncthreads();
  if (t == 0) {
    spart[(k * 8 + c) * 2]     = mx;
    spart[(k * 8 + c) * 2 + 1] = shs[0] + shs[1] + shs[2] + shs[3];
  }
}

// ---------------- fused: head stats from spart; w[n]=sum_k softmax; partial col-sums (bf16 x) ----
__global__ void weighted_part_kernel(const unsigned short* __restrict__ xb,
                                     const float* __restrict__ scores,
                                     const float* __restrict__ spart,
                                     float* __restrict__ wp1,
                                     float* __restrict__ wp2) {
  __shared__ float wrow[128];
  __shared__ float sm[16], srz[16];
  const int d = blockIdx.x * 256 + threadIdx.x;  // grid.x = 4
  const int nc = blockIdx.y;                     // 64 chunks of 128 rows
  if (threadIdx.x < 16) {
    const int k = threadIdx.x;
    float m = -1e30f;
    #pragma unroll
    for (int c = 0; c < 8; ++c) m = fmaxf(m, spart[(k * 8 + c) * 2]);
    float S = 0.f;
    #pragma unroll
    for (int c = 0; c < 8; ++c)
      S += spart[(k * 8 + c) * 2 + 1] * __expf(spart[(k * 8 + c) * 2] - m);
    sm[k] = m; srz[k] = 1.f / S;
  }
  __syncthreads();
  if (threadIdx.x < 128) {
    const int n = nc * 128 + threadIdx.x;
    float s = 0.f;
    #pragma unroll
    for (int k = 0; k < NHEAD; ++k)
      s += __expf(scores[(size_t)k * N_PATCH + n] - sm[k]) * srz[k];
    wrow[threadIdx.x] = s;
  }
  __syncthreads();
  float a1 = 0.f, a2 = 0.f;
  for (int i = 0; i < 128; ++i) {
    unsigned uv = xb[(size_t)(nc * 128 + i) * DIM + d];
    float xv = __uint_as_float(uv << 16);
    a1 += wrow[i] * xv;
    a2 += xv;
  }
  wp1[nc * DIM + d] = a1;
  wp2[nc * DIM + d] = a2;
}

__global__ void reduce_vec_kernel(const float* __restrict__ wp1,
                                  const float* __restrict__ wp2,
                                  float* __restrict__ y1,
                                  float* __restrict__ mvec) {
  int d = blockIdx.x * 256 + threadIdx.x;
  float s1 = 0.f, s2 = 0.f;
  #pragma unroll
  for (int i = 0; i < 64; ++i) {
    s1 += wp1[i * DIM + d];
    s2 += wp2[i * DIM + d];
  }
  y1[d] = s1;
  mvec[d] = s2 * (1.f / (float)N_PATCH);
}

// ---------------- one-dispatch GEMV: in-block split-K (4 kc x 64 j), LDS reduce ----
__global__ void gemv_fused_kernel(const float* __restrict__ in,
                                  const float* __restrict__ W,
                                  const float* __restrict__ bias,
                                  const float* __restrict__ extra, float scale,
                                  int do_relu, float* __restrict__ out,
                                  int In, int Out) {
  __shared__ float red[4][64];
  const int jl = threadIdx.x & 63, kc = threadIdx.x >> 6;
  const int j = blockIdx.x * 64 + jl;
  const int chunk = In >> 2;
  const float* Wp = W + (size_t)(kc * chunk) * Out + j;
  const float* ip = in + kc * chunk;
  float acc = 0.f;
  #pragma unroll 4
  for (int d = 0; d < chunk; ++d) acc += ip[d] * Wp[(size_t)d * Out];
  if (kc) red[kc][jl] = acc;
  __syncthreads();
  if (kc == 0) {
    float v = bias[j] + acc + red[1][jl] + red[2][jl] + red[3][jl];
    if (extra) v += extra[j];
    v *= scale;
    if (do_relu) v = fmaxf(v, 0.f);
    out[j] = v;
  }
}

// ---------------- fused: c3 = relu(c2@cW3+cb3); logits = c3@cW4+cb4; softmax ----
__global__ void c3_final_kernel(const float* __restrict__ c2,
                                const float* __restrict__ W3,
                                const float* __restrict__ b3,
                                const float* __restrict__ W4,
                                const float* __restrict__ b4,
                                float* __restrict__ out) {
  __shared__ float c3s[256];
  __shared__ float logits[9];
  const int t = threadIdx.x;   // 256
  float acc = b3[t];
  #pragma unroll 4
  for (int d = 0; d < 512; ++d) acc += c2[d] * W3[(size_t)d * 256 + t];
  c3s[t] = fmaxf(acc, 0.f);
  __syncthreads();
  if (t < 9) {
    float l = b4[t];
    for (int d = 0; d < 256; ++d) l += c3s[d] * W4[d * 9 + t];
    logits[t] = l;
  }
  __syncthreads();
  if (t == 0) {
    float mx = logits[0];
    for (int j = 1; j < 9; ++j) mx = fmaxf(mx, logits[j]);
    float e[9], s = 0.f;
    for (int j = 0; j < 9; ++j) { e[j] = expf(logits[j] - mx); s += e[j]; }
    for (int j = 0; j < 9; ++j) out[j] = e[j] / s;
  }
}

extern "C" void kernel_launch(void* const* d_in, const int* in_sizes, int n_in,
                              void* d_out, int out_size, void* d_ws, size_t ws_size,
                              hipStream_t stream) {
  (void)in_sizes; (void)n_in; (void)out_size; (void)ws_size;
  const float* x   = (const float*)d_in[0];
  const float* Vw  = (const float*)d_in[1];
  const float* Vb  = (const float*)d_in[2];
  const float* Uw  = (const float*)d_in[3];
  const float* Ub  = (const float*)d_in[4];
  const float* ww  = (const float*)d_in[5];
  // d_in[6] = wb: constant per head -> softmax invariant -> unused
  const float* pW1 = (const float*)d_in[7];
  const float* pb1 = (const float*)d_in[8];
  const float* pW2 = (const float*)d_in[9];
  const float* pb2 = (const float*)d_in[10];
  const float* cW1 = (const float*)d_in[11];
  const float* cb1 = (const float*)d_in[12];
  const float* cW2 = (const float*)d_in[13];
  const float* cb2 = (const float*)d_in[14];
  const float* cW3 = (const float*)d_in[15];
  const float* cb3 = (const float*)d_in[16];
  const float* cW4 = (const float*)d_in[17];
  const float* cb4 = (const float*)d_in[18];
  float* out = (float*)d_out;

  char* ws = (char*)d_ws;
  size_t o = 0;
  auto alloc = [&](size_t bytes) -> char* {
    char* p = ws + o;
    o += (bytes + 255) & ~(size_t)255;
    return p;
  };
  unsigned short* xb  = (unsigned short*)alloc((size_t)N_PATCH * DIM * 2);      // 16 MB
  unsigned short* Wpt = (unsigned short*)alloc((size_t)NHEAD * 1024 * DIM * 2); // 32 MB
  float* part   = (float*)alloc((size_t)16 * NHEAD * N_PATCH * 4);              // 8 MB
  float* scores = (float*)alloc((size_t)NHEAD * N_PATCH * 4);
  float* spart  = (float*)alloc(NHEAD * 8 * 2 * 4);
  float* wp1    = (float*)alloc(64 * DIM * 4);
  float* wp2    = (float*)alloc(64 * DIM * 4);
  float* y1     = (float*)alloc(DIM * 4);
  float* mvec   = (float*)alloc(DIM * 4);
  float* h1     = (float*)alloc(HID * 4);
  float* aggr   = (float*)alloc(DIM * 4);
  float* c1     = (float*)alloc(1024 * 4);
  float* c2     = (float*)alloc(512 * 4);

  prep_kernel<<<4096, 256, 0, stream>>>(x, xb, Vw, Uw, Wpt);
  gemm_scores_kernel<<<2048, 1024, 0, stream>>>(xb, Wpt, Vb, Ub, ww, part);
  scores_part_kernel<<<128, 256, 0, stream>>>(part, scores, spart);
  weighted_part_kernel<<<dim3(4, 64), 256, 0, stream>>>(xb, scores, spart, wp1, wp2);
  reduce_vec_kernel<<<4, 256, 0, stream>>>(wp1, wp2, y1, mvec);
  gemv_fused_kernel<<<8, 256, 0, stream>>>(mvec, pW1, pb1, nullptr, 1.f, 1, h1, DIM, HID);
  gemv_fused_kernel<<<16, 256, 0, stream>>>(h1, pW2, pb2, y1, 1.f / 17.f, 0, aggr, HID, DIM);
  gemv_fused_kernel<<<16, 256, 0, stream>>>(aggr, cW1, cb1, nullptr, 1.f, 1, c1, 1024, 1024);
  gemv_fused_kernel<<<8, 256, 0, stream>>>(c1, cW2, cb2, nullptr, 1.f, 1, c2, 1024, 512);
  c3_final_kernel<<<1, 256, 0, stream>>>(c2, cW3, cb3, cW4, cb4, out);
}